// Round 3
// baseline (721.781 us; speedup 1.0000x reference)
//
#include <hip/hip_runtime.h>

typedef __bf16 bf16x8 __attribute__((ext_vector_type(8)));
typedef float f32x4 __attribute__((ext_vector_type(4)));
typedef unsigned int u32x4 __attribute__((ext_vector_type(4)));
typedef unsigned short u16x4 __attribute__((ext_vector_type(4)));

#define S_LEN 2048
#define HDIM  4096
#define KVDIM 1024
#define NHEAD 32
#define NKV   8

__device__ __forceinline__ unsigned short f2b(float x) {
    unsigned int u = __builtin_bit_cast(unsigned int, x);
    u = (u + 0x7FFFu + ((u >> 16) & 1u)) >> 16;
    return (unsigned short)u;
}
__device__ __forceinline__ float b2f(unsigned short b) {
    unsigned int u = ((unsigned int)b) << 16;
    return __builtin_bit_cast(float, u);
}

__device__ __forceinline__ void gl_lds16(const void* g, void* s) {
    __builtin_amdgcn_global_load_lds(
        (const __attribute__((address_space(1))) unsigned int*)g,
        (__attribute__((address_space(3))) unsigned int*)s, 16, 0, 0);
}

// ---------------- fused f32 -> bf16 conversion (all 5 tensors, one launch) ------
// group = 4 elems. Segment sizes (groups): hb 2M, Wq 4M, Wk 1M, Wv 1M, Wo 4M.
// All boundaries are multiples of 256 -> branch is block-uniform.
__global__ void cvt_all(const float* __restrict__ hid, const float* __restrict__ Wq,
                        const float* __restrict__ Wk, const float* __restrict__ Wv,
                        const float* __restrict__ Wo,
                        unsigned short* __restrict__ hb, unsigned short* __restrict__ Wqb,
                        unsigned short* __restrict__ Wkb, unsigned short* __restrict__ Wvb,
                        unsigned short* __restrict__ Wob) {
    int g = blockIdx.x * 256 + threadIdx.x;
    const float* src; unsigned short* dst; int off;
    if (g < 2097152)      { src = hid; dst = hb;  off = g; }
    else if (g < 6291456) { src = Wq;  dst = Wqb; off = g - 2097152; }
    else if (g < 7340032) { src = Wk;  dst = Wkb; off = g - 6291456; }
    else if (g < 8388608) { src = Wv;  dst = Wvb; off = g - 7340032; }
    else                  { src = Wo;  dst = Wob; off = g - 8388608; }
    f32x4 v = ((const f32x4*)src)[off];
    u16x4 o;
    o.x = f2b(v.x); o.y = f2b(v.y); o.z = f2b(v.z); o.w = f2b(v.w);
    ((u16x4*)dst)[off] = o;
}

// ---------------- NT GEMM body: C[M,N] = A[M,K] @ B[N,K]^T ----------------
// MODE 0: C bf16 [M,N]; MODE 1: C bf16 transposed [N,M]; MODE 2: C f32 [M,N]
template <int MODE>
__device__ __forceinline__ void gemm_body(const unsigned short* __restrict__ A,
                                          const unsigned short* __restrict__ B,
                                          void* __restrict__ Cv,
                                          int M, int N, int K, int m0, int n0,
                                          unsigned short (*As)[64], unsigned short (*Bs)[64]) {
    const int tid = threadIdx.x;
    const int w = tid >> 6, lane = tid & 63, quad = lane >> 4, l15 = lane & 15;
    const int wy = w >> 1, wx = w & 1;
    const int srowb = w * 32 + (lane >> 3);
    const int gchunk = (lane & 7) ^ (lane >> 3);
    const int lcol = (lane & 7) * 8;

    f32x4 acc[4][4] = {};

    for (int k0 = 0; k0 < K; k0 += 64) {
#pragma unroll
        for (int p = 0; p < 4; ++p) {
            int r = srowb + p * 8;
            gl_lds16(&A[(size_t)(m0 + r) * K + k0 + gchunk * 8], &As[r][lcol]);
            gl_lds16(&B[(size_t)(n0 + r) * K + k0 + gchunk * 8], &Bs[r][lcol]);
        }
        __syncthreads();
#pragma unroll
        for (int t = 0; t < 2; ++t) {
            bf16x8 af[4], bfr[4];
#pragma unroll
            for (int mb = 0; mb < 4; ++mb)
                af[mb] = *(const bf16x8*)&As[wy * 64 + mb * 16 + l15][(((t * 4 + quad) ^ (l15 & 7)) * 8)];
#pragma unroll
            for (int nb = 0; nb < 4; ++nb)
                bfr[nb] = *(const bf16x8*)&Bs[wx * 64 + nb * 16 + l15][(((t * 4 + quad) ^ (l15 & 7)) * 8)];
#pragma unroll
            for (int mb = 0; mb < 4; ++mb)
#pragma unroll
                for (int nb = 0; nb < 4; ++nb)
                    acc[mb][nb] = __builtin_amdgcn_mfma_f32_16x16x32_bf16(af[mb], bfr[nb], acc[mb][nb], 0, 0, 0);
        }
        __syncthreads();
    }
#pragma unroll
    for (int mb = 0; mb < 4; ++mb)
#pragma unroll
        for (int nb = 0; nb < 4; ++nb)
#pragma unroll
            for (int r = 0; r < 4; ++r) {
                int row = m0 + wy * 64 + mb * 16 + quad * 4 + r;
                int col = n0 + wx * 64 + nb * 16 + l15;
                float v = acc[mb][nb][r];
                if (MODE == 0)
                    ((unsigned short*)Cv)[(size_t)row * N + col] = f2b(v);
                else if (MODE == 1)
                    ((unsigned short*)Cv)[(size_t)col * M + row] = f2b(v);
                else
                    ((float*)Cv)[(size_t)row * N + col] = v;
            }
}

// fused QKV projection: grid (48,16) = 768 blocks (3/CU)
__global__ __launch_bounds__(256) void gemm_qkv(const unsigned short* __restrict__ A,
                                                const unsigned short* __restrict__ Bq,
                                                const unsigned short* __restrict__ Bk,
                                                const unsigned short* __restrict__ Bv,
                                                void* __restrict__ Cq, void* __restrict__ Ck,
                                                void* __restrict__ Cvt) {
    __shared__ unsigned short As[128][64];
    __shared__ unsigned short Bs[128][64];
    const int bx = blockIdx.x, m0 = blockIdx.y * 128;
    if (bx < 32)
        gemm_body<0>(A, Bq, Cq, S_LEN, HDIM, HDIM, m0, bx * 128, As, Bs);
    else if (bx < 40)
        gemm_body<0>(A, Bk, Ck, S_LEN, KVDIM, HDIM, m0, (bx - 32) * 128, As, Bs);
    else
        gemm_body<1>(A, Bv, Cvt, S_LEN, KVDIM, HDIM, m0, (bx - 40) * 128, As, Bs);
}

// output projection (f32 out)
__global__ __launch_bounds__(256) void gemm_o(const unsigned short* __restrict__ A,
                                              const unsigned short* __restrict__ B,
                                              void* __restrict__ Cv) {
    __shared__ unsigned short As[128][64];
    __shared__ unsigned short Bs[128][64];
    gemm_body<2>(A, B, Cv, S_LEN, HDIM, HDIM, blockIdx.y * 128, blockIdx.x * 128, As, Bs);
}

// ---------------- RoPE (in-place, bf16 Q [S,4096] and K [S,1024]) ----------------
__global__ void rope_kernel(unsigned short* __restrict__ Q, unsigned short* __restrict__ Kc,
                            const int* __restrict__ pos_ids) {
    int tid = blockIdx.x * 256 + threadIdx.x;
    int j = tid & 63;
    int head = (tid >> 6) % (NHEAD + NKV);
    int s = tid / (64 * (NHEAD + NKV));
    float pos = (float)pos_ids[s];
    float inv = exp2f(-(float)j * 0.20762050593046f);
    float ang = pos * inv;
    float sn, cs;
    __sincosf(ang, &sn, &cs);
    unsigned short* p;
    if (head < NHEAD)
        p = Q + (size_t)s * HDIM + head * 128;
    else
        p = Kc + (size_t)s * KVDIM + (head - NHEAD) * 128;
    float x1 = b2f(p[j]), x2 = b2f(p[j + 64]);
    p[j] = f2b(x1 * cs - x2 * sn);
    p[j + 64] = f2b(x2 * cs + x1 * sn);
}

// ---------------- causal GQA flash attention (S^T orientation, 128 q/block) -----
// grid = (NHEAD, S/128); qb = (S/128-1) - blockIdx.y (heavy first)
// wave w owns q-cols [qb*128 + w*32, +32) as two 16-col tiles u=0,1
__global__ __launch_bounds__(256, 3) void attn_fwd(const unsigned short* __restrict__ Q,
                                                   const unsigned short* __restrict__ Kb,
                                                   const unsigned short* __restrict__ Vt,
                                                   unsigned short* __restrict__ O) {
    __shared__ unsigned short Ks[64][128];     // XOR-chunk swizzled
    __shared__ unsigned short Vts[128][64];    // XOR-chunk swizzled
    __shared__ unsigned short Ps[4][2][16][80];

    const int qb = (gridDim.y - 1) - blockIdx.y;
    const int h = blockIdx.x, kvh = h >> 2;
    const int tid = threadIdx.x, w = tid >> 6, lane = tid & 63;
    const int quad = lane >> 4, l15 = lane & 15;

    bf16x8 aq[2][4];
#pragma unroll
    for (int u = 0; u < 2; ++u)
#pragma unroll
        for (int t = 0; t < 4; ++t)
            aq[u][t] = *(const bf16x8*)&Q[(size_t)(qb * 128 + w * 32 + u * 16 + l15) * HDIM +
                                          h * 128 + t * 32 + quad * 8];

    f32x4 o[2][8] = {};
    float m_s[2] = {-3.0e38f, -3.0e38f}, l_s[2] = {0.f, 0.f};
    const float cexp = 0.08838834764831845f * 1.4426950408889634f;  // 1/sqrt(128)*log2(e)

    const int kr0 = tid >> 4, ksg = tid & 15;  // K staging: 16 rows x 16 chunks, x4 passes
    const int vr0 = tid >> 3, vsg = tid & 7;   // V staging: 32 rows x 8 chunks, x4 passes
    const int ktmax = 2 * qb + 1;

    u32x4 kpre[4], vpre[4];
#pragma unroll
    for (int p = 0; p < 4; ++p) {
        kpre[p] = *(const u32x4*)&Kb[(size_t)(kr0 + p * 16) * KVDIM + kvh * 128 + ksg * 8];
        vpre[p] = *(const u32x4*)&Vt[(size_t)(kvh * 128 + vr0 + p * 32) * S_LEN + vsg * 8];
    }

    for (int kt = 0; kt <= ktmax; ++kt) {
#pragma unroll
        for (int p = 0; p < 4; ++p) {
            int rk = kr0 + p * 16;
            *(u32x4*)&Ks[rk][(ksg ^ (rk & 7)) * 8] = kpre[p];
            int rv = vr0 + p * 32;
            *(u32x4*)&Vts[rv][(vsg ^ (rv & 7)) * 8] = vpre[p];
        }
        __syncthreads();
        if (kt < ktmax) {
            const int k0n = kt * 64 + 64;
#pragma unroll
            for (int p = 0; p < 4; ++p) {
                kpre[p] = *(const u32x4*)&Kb[(size_t)(k0n + kr0 + p * 16) * KVDIM + kvh * 128 + ksg * 8];
                vpre[p] = *(const u32x4*)&Vt[(size_t)(kvh * 128 + vr0 + p * 32) * S_LEN + k0n + vsg * 8];
            }
        }

        const int k0 = kt * 64;
#pragma unroll
        for (int u = 0; u < 2; ++u) {
            const int qmin = qb * 128 + w * 32 + u * 16;  // wave-uniform min q of this col-set
            if (k0 > qmin + 15) continue;                 // fully masked: skip (wave-uniform)

            // S^T = K Q^T : rows = k (64), cols = q (16)
            f32x4 sc[4] = {};
#pragma unroll
            for (int t = 0; t < 4; ++t)
#pragma unroll
                for (int mb = 0; mb < 4; ++mb) {
                    bf16x8 ak = *(const bf16x8*)&Ks[mb * 16 + l15][((t * 4 + quad) ^ (l15 & 7)) * 8];
                    sc[mb] = __builtin_amdgcn_mfma_f32_16x16x32_bf16(ak, aq[u][t], sc[mb], 0, 0, 0);
                }

            const bool need_mask = (k0 + 63 > qmin);
            const int qg = qmin + l15;
            float mx = -3.0e38f;
#pragma unroll
            for (int mb = 0; mb < 4; ++mb)
#pragma unroll
                for (int r = 0; r < 4; ++r) {
                    float v = sc[mb][r] * cexp;
                    if (need_mask && (k0 + mb * 16 + quad * 4 + r > qg)) v = -3.0e38f;
                    mx = fmaxf(mx, v);
                }
            mx = fmaxf(mx, __shfl_xor(mx, 16, 64));
            mx = fmaxf(mx, __shfl_xor(mx, 32, 64));
            float mnew = fmaxf(m_s[u], mx);
            float alpha = exp2f(m_s[u] - mnew);
            m_s[u] = mnew;
            float sum = 0.f;
#pragma unroll
            for (int mb = 0; mb < 4; ++mb) {
                u16x4 pk;
#pragma unroll
                for (int r = 0; r < 4; ++r) {
                    float v = sc[mb][r] * cexp;
                    float pp = (need_mask && (k0 + mb * 16 + quad * 4 + r > qg))
                                   ? 0.f : exp2f(v - mnew);
                    sum += pp;
                    ((unsigned short*)&pk)[r] = f2b(pp);
                }
                *(u16x4*)&Ps[w][u][l15][mb * 16 + quad * 4] = pk;
            }
            sum += __shfl_xor(sum, 16, 64);
            sum += __shfl_xor(sum, 32, 64);
            l_s[u] = l_s[u] * alpha + sum;

            float a4[4];
#pragma unroll
            for (int r = 0; r < 4; ++r) a4[r] = __shfl(alpha, quad * 20 + r, 64);
#pragma unroll
            for (int db = 0; db < 8; ++db)
#pragma unroll
                for (int r = 0; r < 4; ++r) o[u][db][r] *= a4[r];

            bf16x8 pa[2];
#pragma unroll
            for (int t = 0; t < 2; ++t)
                pa[t] = *(const bf16x8*)&Ps[w][u][l15][t * 32 + quad * 8];
#pragma unroll
            for (int db = 0; db < 8; ++db)
#pragma unroll
                for (int t = 0; t < 2; ++t) {
                    bf16x8 vb = *(const bf16x8*)&Vts[db * 16 + l15][((t * 4 + quad) ^ (l15 & 7)) * 8];
                    o[u][db] = __builtin_amdgcn_mfma_f32_16x16x32_bf16(pa[t], vb, o[u][db], 0, 0, 0);
                }
        }
        __syncthreads();
    }

#pragma unroll
    for (int u = 0; u < 2; ++u) {
        float linv[4];
#pragma unroll
        for (int r = 0; r < 4; ++r) linv[r] = 1.0f / __shfl(l_s[u], quad * 20 + r, 64);
        const int qrow_base = qb * 128 + w * 32 + u * 16 + quad * 4;
#pragma unroll
        for (int db = 0; db < 8; ++db)
#pragma unroll
            for (int r = 0; r < 4; ++r)
                O[(size_t)(qrow_base + r) * HDIM + h * 128 + db * 16 + l15] =
                    f2b(o[u][db][r] * linv[r]);
    }
}

extern "C" void kernel_launch(void* const* d_in, const int* in_sizes, int n_in,
                              void* d_out, int out_size, void* d_ws, size_t ws_size,
                              hipStream_t stream) {
    const float* hid = (const float*)d_in[0];
    const int* pos   = (const int*)d_in[1];
    const float* Wq  = (const float*)d_in[2];
    const float* Wk  = (const float*)d_in[3];
    const float* Wv  = (const float*)d_in[4];
    const float* Wo  = (const float*)d_in[5];
    float* out = (float*)d_out;

    char* ws = (char*)d_ws;
    unsigned short* hb   = (unsigned short*)(ws);               // 16 MiB  [S,H]
    unsigned short* Wqb  = (unsigned short*)(ws + 16777216);    // 32 MiB
    unsigned short* Wkb  = (unsigned short*)(ws + 50331648);    // 8 MiB
    unsigned short* Wvb  = (unsigned short*)(ws + 58720256);    // 8 MiB
    unsigned short* Wob  = (unsigned short*)(ws + 67108864);    // 32 MiB
    unsigned short* Qw   = (unsigned short*)(ws + 100663296);   // 16 MiB
    unsigned short* Kw   = (unsigned short*)(ws + 117440512);   // 4 MiB
    unsigned short* Vtw  = (unsigned short*)(ws + 121634816);   // 4 MiB
    unsigned short* attw = hb;  // reuse hidden region (consumed before attention writes)

    // 1. f32 -> bf16 (single launch)
    cvt_all<<<49152, 256, 0, stream>>>(hid, Wq, Wk, Wv, Wo, hb, Wqb, Wkb, Wvb, Wob);

    // 2. fused QKV projection
    gemm_qkv<<<dim3(48, S_LEN / 128), 256, 0, stream>>>(hb, Wqb, Wkb, Wvb, Qw, Kw, Vtw);

    // 3. RoPE on Q,K
    rope_kernel<<<S_LEN * (NHEAD + NKV) * 64 / 256, 256, 0, stream>>>(Qw, Kw, pos);

    // 4. causal GQA attention (128 q-rows/block, heavy-first)
    attn_fwd<<<dim3(NHEAD, S_LEN / 128), 256, 0, stream>>>(Qw, Kw, Vtw, attw);

    // 5. output projection -> f32
    gemm_o<<<dim3(HDIM / 128, S_LEN / 128), 256, 0, stream>>>(attw, Wob, out);
}

// Round 4
// 588.237 us; speedup vs baseline: 1.2270x; 1.2270x over previous
//
#include <hip/hip_runtime.h>

typedef __bf16 bf16x8 __attribute__((ext_vector_type(8)));
typedef float f32x4 __attribute__((ext_vector_type(4)));
typedef unsigned int u32x4 __attribute__((ext_vector_type(4)));
typedef unsigned short u16x4 __attribute__((ext_vector_type(4)));

#define S_LEN 2048
#define HDIM  4096
#define KVDIM 1024
#define NHEAD 32
#define NKV   8

__device__ __forceinline__ unsigned short f2b(float x) {
    unsigned int u = __builtin_bit_cast(unsigned int, x);
    u = (u + 0x7FFFu + ((u >> 16) & 1u)) >> 16;
    return (unsigned short)u;
}
__device__ __forceinline__ float b2f(unsigned short b) {
    unsigned int u = ((unsigned int)b) << 16;
    return __builtin_bit_cast(float, u);
}

__device__ __forceinline__ void gl_lds16(const void* g, void* s) {
    __builtin_amdgcn_global_load_lds(
        (const __attribute__((address_space(1))) unsigned int*)g,
        (__attribute__((address_space(3))) unsigned int*)s, 16, 0, 0);
}

// ---------------- fused f32 -> bf16 conversion (all 5 tensors, one launch) ------
__global__ void cvt_all(const float* __restrict__ hid, const float* __restrict__ Wq,
                        const float* __restrict__ Wk, const float* __restrict__ Wv,
                        const float* __restrict__ Wo,
                        unsigned short* __restrict__ hb, unsigned short* __restrict__ Wqb,
                        unsigned short* __restrict__ Wkb, unsigned short* __restrict__ Wvb,
                        unsigned short* __restrict__ Wob) {
    int g = blockIdx.x * 256 + threadIdx.x;
    const float* src; unsigned short* dst; int off;
    if (g < 2097152)      { src = hid; dst = hb;  off = g; }
    else if (g < 6291456) { src = Wq;  dst = Wqb; off = g - 2097152; }
    else if (g < 7340032) { src = Wk;  dst = Wkb; off = g - 6291456; }
    else if (g < 8388608) { src = Wv;  dst = Wvb; off = g - 7340032; }
    else                  { src = Wo;  dst = Wob; off = g - 8388608; }
    f32x4 v = ((const f32x4*)src)[off];
    u16x4 o;
    o.x = f2b(v.x); o.y = f2b(v.y); o.z = f2b(v.z); o.w = f2b(v.w);
    ((u16x4*)dst)[off] = o;
}

// ---------------- NT GEMM body: C[M,N] = A[M,K] @ B[N,K]^T ----------------
template <int MODE>
__device__ __forceinline__ void gemm_body(const unsigned short* __restrict__ A,
                                          const unsigned short* __restrict__ B,
                                          void* __restrict__ Cv,
                                          int M, int N, int K, int m0, int n0,
                                          unsigned short (*As)[64], unsigned short (*Bs)[64]) {
    const int tid = threadIdx.x;
    const int w = tid >> 6, lane = tid & 63, quad = lane >> 4, l15 = lane & 15;
    const int wy = w >> 1, wx = w & 1;
    const int srowb = w * 32 + (lane >> 3);
    const int gchunk = (lane & 7) ^ (lane >> 3);
    const int lcol = (lane & 7) * 8;

    f32x4 acc[4][4] = {};

    for (int k0 = 0; k0 < K; k0 += 64) {
#pragma unroll
        for (int p = 0; p < 4; ++p) {
            int r = srowb + p * 8;
            gl_lds16(&A[(size_t)(m0 + r) * K + k0 + gchunk * 8], &As[r][lcol]);
            gl_lds16(&B[(size_t)(n0 + r) * K + k0 + gchunk * 8], &Bs[r][lcol]);
        }
        __syncthreads();
#pragma unroll
        for (int t = 0; t < 2; ++t) {
            bf16x8 af[4], bfr[4];
#pragma unroll
            for (int mb = 0; mb < 4; ++mb)
                af[mb] = *(const bf16x8*)&As[wy * 64 + mb * 16 + l15][(((t * 4 + quad) ^ (l15 & 7)) * 8)];
#pragma unroll
            for (int nb = 0; nb < 4; ++nb)
                bfr[nb] = *(const bf16x8*)&Bs[wx * 64 + nb * 16 + l15][(((t * 4 + quad) ^ (l15 & 7)) * 8)];
#pragma unroll
            for (int mb = 0; mb < 4; ++mb)
#pragma unroll
                for (int nb = 0; nb < 4; ++nb)
                    acc[mb][nb] = __builtin_amdgcn_mfma_f32_16x16x32_bf16(af[mb], bfr[nb], acc[mb][nb], 0, 0, 0);
        }
        __syncthreads();
    }
#pragma unroll
    for (int mb = 0; mb < 4; ++mb)
#pragma unroll
        for (int nb = 0; nb < 4; ++nb)
#pragma unroll
            for (int r = 0; r < 4; ++r) {
                int row = m0 + wy * 64 + mb * 16 + quad * 4 + r;
                int col = n0 + wx * 64 + nb * 16 + l15;
                float v = acc[mb][nb][r];
                if (MODE == 0)
                    ((unsigned short*)Cv)[(size_t)row * N + col] = f2b(v);
                else if (MODE == 1)
                    ((unsigned short*)Cv)[(size_t)col * M + row] = f2b(v);
                else
                    ((float*)Cv)[(size_t)row * N + col] = v;
            }
}

// fused QKV projection: grid (48,16) = 768 blocks (3/CU)
__global__ __launch_bounds__(256) void gemm_qkv(const unsigned short* __restrict__ A,
                                                const unsigned short* __restrict__ Bq,
                                                const unsigned short* __restrict__ Bk,
                                                const unsigned short* __restrict__ Bv,
                                                void* __restrict__ Cq, void* __restrict__ Ck,
                                                void* __restrict__ Cvt) {
    __shared__ unsigned short As[128][64];
    __shared__ unsigned short Bs[128][64];
    const int bx = blockIdx.x, m0 = blockIdx.y * 128;
    if (bx < 32)
        gemm_body<0>(A, Bq, Cq, S_LEN, HDIM, HDIM, m0, bx * 128, As, Bs);
    else if (bx < 40)
        gemm_body<0>(A, Bk, Ck, S_LEN, KVDIM, HDIM, m0, (bx - 32) * 128, As, Bs);
    else
        gemm_body<1>(A, Bv, Cvt, S_LEN, KVDIM, HDIM, m0, (bx - 40) * 128, As, Bs);
}

__global__ __launch_bounds__(256) void gemm_o(const unsigned short* __restrict__ A,
                                              const unsigned short* __restrict__ B,
                                              void* __restrict__ Cv) {
    __shared__ unsigned short As[128][64];
    __shared__ unsigned short Bs[128][64];
    gemm_body<2>(A, B, Cv, S_LEN, HDIM, HDIM, blockIdx.y * 128, blockIdx.x * 128, As, Bs);
}

// ---------------- RoPE (in-place, bf16 Q [S,4096] and K [S,1024]) ----------------
__global__ void rope_kernel(unsigned short* __restrict__ Q, unsigned short* __restrict__ Kc,
                            const int* __restrict__ pos_ids) {
    int tid = blockIdx.x * 256 + threadIdx.x;
    int j = tid & 63;
    int head = (tid >> 6) % (NHEAD + NKV);
    int s = tid / (64 * (NHEAD + NKV));
    float pos = (float)pos_ids[s];
    float inv = exp2f(-(float)j * 0.20762050593046f);
    float ang = pos * inv;
    float sn, cs;
    __sincosf(ang, &sn, &cs);
    unsigned short* p;
    if (head < NHEAD)
        p = Q + (size_t)s * HDIM + head * 128;
    else
        p = Kc + (size_t)s * KVDIM + (head - NHEAD) * 128;
    float x1 = b2f(p[j]), x2 = b2f(p[j + 64]);
    p[j] = f2b(x1 * cs - x2 * sn);
    p[j + 64] = f2b(x2 * cs + x1 * sn);
}

// ---------------- causal GQA flash attention ----------------
// 128 q/block, 4 waves x 32q (two 16-col u-tiles). gl_lds16 staging (no reg
// prefetch -> no spill). ak/vb LDS reads shared across both u-tiles.
// grid (NHEAD, 16); qb = 15 - blockIdx.y.
__global__ __launch_bounds__(256) void attn_fwd(const unsigned short* __restrict__ Q,
                                                const unsigned short* __restrict__ Kb,
                                                const unsigned short* __restrict__ Vt,
                                                unsigned short* __restrict__ O) {
    __shared__ unsigned short Ks[64][128];   // [k][d]  16B-chunk XOR-swizzled by row&7
    __shared__ unsigned short Vts[128][64];  // [d][k]  XOR-swizzled
    __shared__ unsigned short Ps[4][2][16][72];  // stride 72: 2-way (free) stores

    const int qb = (gridDim.y - 1) - blockIdx.y;
    const int h = blockIdx.x, kvh = h >> 2;
    const int tid = threadIdx.x, w = tid >> 6, lane = tid & 63;
    const int quad = lane >> 4, l15 = lane & 15;

    // staging indices (K: 16 rows x 16 chunks per pass; V: 32 rows x 8 chunks)
    const int krow = tid >> 4, kslot = tid & 15;
    const int vrow = tid >> 3, vslot = tid & 7;

    bf16x8 aq[2][4];
#pragma unroll
    for (int u = 0; u < 2; ++u)
#pragma unroll
        for (int t = 0; t < 4; ++t)
            aq[u][t] = *(const bf16x8*)&Q[(size_t)(qb * 128 + w * 32 + u * 16 + l15) * HDIM +
                                          h * 128 + t * 32 + quad * 8];

    f32x4 o[2][8] = {};
    float m_s[2] = {-3.0e38f, -3.0e38f}, l_s[2] = {0.f, 0.f};
    const float cexp = 0.08838834764831845f * 1.4426950408889634f;  // 1/sqrt(128)*log2(e)
    const int ktmax = 2 * qb + 1;

    for (int kt = 0; kt <= ktmax; ++kt) {
        const int k0 = kt * 64;
        // stage K tile (64x128) and V^T tile (128x64) via async global->LDS
#pragma unroll
        for (int p = 0; p < 4; ++p) {
            int r = p * 16 + krow;
            int gc = kslot ^ (r & 7);
            gl_lds16(&Kb[(size_t)(k0 + r) * KVDIM + kvh * 128 + gc * 8], &Ks[r][kslot * 8]);
        }
#pragma unroll
        for (int p = 0; p < 4; ++p) {
            int r = p * 32 + vrow;
            int gc = vslot ^ (r & 7);
            gl_lds16(&Vt[(size_t)(kvh * 128 + r) * S_LEN + k0 + gc * 8], &Vts[r][vslot * 8]);
        }
        __syncthreads();

        // S^T = K Q^T for both u-tiles; ak read once, used twice
        f32x4 sc[2][4] = {};
#pragma unroll
        for (int t = 0; t < 4; ++t)
#pragma unroll
            for (int mb = 0; mb < 4; ++mb) {
                bf16x8 ak = *(const bf16x8*)&Ks[mb * 16 + l15][((4 * t + quad) ^ (l15 & 7)) * 8];
                sc[0][mb] = __builtin_amdgcn_mfma_f32_16x16x32_bf16(ak, aq[0][t], sc[0][mb], 0, 0, 0);
                sc[1][mb] = __builtin_amdgcn_mfma_f32_16x16x32_bf16(ak, aq[1][t], sc[1][mb], 0, 0, 0);
            }

        // online softmax per u-tile (branchless; fully-masked tiles are no-ops)
#pragma unroll
        for (int u = 0; u < 2; ++u) {
            const int qmin = qb * 128 + w * 32 + u * 16;
            const bool need_mask = (k0 + 63 > qmin);
            const int qg = qmin + l15;
            float mx = -3.0e38f;
#pragma unroll
            for (int mb = 0; mb < 4; ++mb)
#pragma unroll
                for (int r = 0; r < 4; ++r) {
                    float v = sc[u][mb][r] * cexp;
                    if (need_mask && (k0 + mb * 16 + quad * 4 + r > qg)) v = -3.0e38f;
                    mx = fmaxf(mx, v);
                }
            mx = fmaxf(mx, __shfl_xor(mx, 16, 64));
            mx = fmaxf(mx, __shfl_xor(mx, 32, 64));
            float mnew = fmaxf(m_s[u], mx);
            float alpha = exp2f(m_s[u] - mnew);
            m_s[u] = mnew;
            float sum = 0.f;
#pragma unroll
            for (int mb = 0; mb < 4; ++mb) {
                u16x4 pk;
#pragma unroll
                for (int r = 0; r < 4; ++r) {
                    float v = sc[u][mb][r] * cexp;
                    float pp = (need_mask && (k0 + mb * 16 + quad * 4 + r > qg))
                                   ? 0.f : exp2f(v - mnew);
                    sum += pp;
                    ((unsigned short*)&pk)[r] = f2b(pp);
                }
                *(u16x4*)&Ps[w][u][l15][mb * 16 + quad * 4] = pk;
            }
            sum += __shfl_xor(sum, 16, 64);
            sum += __shfl_xor(sum, 32, 64);
            l_s[u] = l_s[u] * alpha + sum;

            float a4[4];
#pragma unroll
            for (int r = 0; r < 4; ++r) a4[r] = __shfl(alpha, quad * 20 + r, 64);
#pragma unroll
            for (int db = 0; db < 8; ++db)
#pragma unroll
                for (int r = 0; r < 4; ++r) o[u][db][r] *= a4[r];
        }

        // O += P V for both u-tiles; vb read once, used twice
        bf16x8 pa[2][2];
#pragma unroll
        for (int u = 0; u < 2; ++u)
#pragma unroll
            for (int t = 0; t < 2; ++t)
                pa[u][t] = *(const bf16x8*)&Ps[w][u][l15][t * 32 + quad * 8];
#pragma unroll
        for (int db = 0; db < 8; ++db)
#pragma unroll
            for (int t = 0; t < 2; ++t) {
                bf16x8 vb = *(const bf16x8*)&Vts[db * 16 + l15][((4 * t + quad) ^ (l15 & 7)) * 8];
                o[0][db] = __builtin_amdgcn_mfma_f32_16x16x32_bf16(pa[0][t], vb, o[0][db], 0, 0, 0);
                o[1][db] = __builtin_amdgcn_mfma_f32_16x16x32_bf16(pa[1][t], vb, o[1][db], 0, 0, 0);
            }
        __syncthreads();
    }

#pragma unroll
    for (int u = 0; u < 2; ++u) {
        float linv[4];
#pragma unroll
        for (int r = 0; r < 4; ++r) linv[r] = 1.0f / __shfl(l_s[u], quad * 20 + r, 64);
        const int qrow_base = qb * 128 + w * 32 + u * 16 + quad * 4;
#pragma unroll
        for (int db = 0; db < 8; ++db)
#pragma unroll
            for (int r = 0; r < 4; ++r)
                O[(size_t)(qrow_base + r) * HDIM + h * 128 + db * 16 + l15] =
                    f2b(o[u][db][r] * linv[r]);
    }
}

extern "C" void kernel_launch(void* const* d_in, const int* in_sizes, int n_in,
                              void* d_out, int out_size, void* d_ws, size_t ws_size,
                              hipStream_t stream) {
    const float* hid = (const float*)d_in[0];
    const int* pos   = (const int*)d_in[1];
    const float* Wq  = (const float*)d_in[2];
    const float* Wk  = (const float*)d_in[3];
    const float* Wv  = (const float*)d_in[4];
    const float* Wo  = (const float*)d_in[5];
    float* out = (float*)d_out;

    char* ws = (char*)d_ws;
    unsigned short* hb   = (unsigned short*)(ws);               // 16 MiB  [S,H]
    unsigned short* Wqb  = (unsigned short*)(ws + 16777216);    // 32 MiB
    unsigned short* Wkb  = (unsigned short*)(ws + 50331648);    // 8 MiB
    unsigned short* Wvb  = (unsigned short*)(ws + 58720256);    // 8 MiB
    unsigned short* Wob  = (unsigned short*)(ws + 67108864);    // 32 MiB
    unsigned short* Qw   = (unsigned short*)(ws + 100663296);   // 16 MiB
    unsigned short* Kw   = (unsigned short*)(ws + 117440512);   // 4 MiB
    unsigned short* Vtw  = (unsigned short*)(ws + 121634816);   // 4 MiB
    unsigned short* attw = hb;  // reuse hidden region (consumed before attention writes)

    cvt_all<<<49152, 256, 0, stream>>>(hid, Wq, Wk, Wv, Wo, hb, Wqb, Wkb, Wvb, Wob);
    gemm_qkv<<<dim3(48, S_LEN / 128), 256, 0, stream>>>(hb, Wqb, Wkb, Wvb, Qw, Kw, Vtw);
    rope_kernel<<<S_LEN * (NHEAD + NKV) * 64 / 256, 256, 0, stream>>>(Qw, Kw, pos);
    attn_fwd<<<dim3(NHEAD, S_LEN / 128), 256, 0, stream>>>(Qw, Kw, Vtw, attw);
    gemm_o<<<dim3(HDIM / 128, S_LEN / 128), 256, 0, stream>>>(attw, Wob, out);
}